// Round 1
// baseline (4025.870 us; speedup 1.0000x reference)
//
#include <hip/hip_runtime.h>
#include <hip/hip_bf16.h>
#include <math.h>

#define B_ 8
#define L_ 2048
#define DM 256
#define DIP 1064
#define DI 512
#define CD 544
#define DSZ 16
#define NH 8
#define HD 64
#define CHUNK 16

// ---------------- embed: h = emb[x] + pos, * mask ----------------
__global__ __launch_bounds__(256) void k_embed(const int* __restrict__ x, const float* __restrict__ mask,
                                               const float* __restrict__ emb, const float* __restrict__ pos,
                                               float* __restrict__ h) {
    int i = blockIdx.x * 256 + threadIdx.x;
    if (i >= B_ * L_ * DM) return;
    int d = i % DM;
    int bl = i / DM;
    int l = bl % L_;
    int tok = x[bl];
    h[i] = (emb[tok * DM + d] + pos[l * DM + d]) * mask[bl];
}

// ---------------- fp32 NT GEMM: C[m,n] = sum_k A[m,k]*Bw[n,k] ----------------
__global__ __launch_bounds__(256) void k_gemm_nt(const float* __restrict__ A, int lda,
                                                 const float* __restrict__ Bw, int ldb,
                                                 float* __restrict__ C, int ldc,
                                                 int M, int N, int K) {
    const int BM = 64, BN = 64, BK = 16;
    __shared__ float As[BK][BM];
    __shared__ float Bs[BK][BN];
    int tid = threadIdx.x;
    int tx = tid & 15, ty = tid >> 4;
    int m0 = blockIdx.x * BM, n0 = blockIdx.y * BN;
    int lr = tid >> 2;         // 0..63 (row within tile)
    int lk = (tid & 3) * 4;    // 0,4,8,12 (k offset)
    float acc[4][4] = {};
    for (int k0 = 0; k0 < K; k0 += BK) {
        float4 av = *(const float4*)(A + (size_t)(m0 + lr) * lda + k0 + lk);
        float4 bv;
        int n = n0 + lr;
        if (n < N) bv = *(const float4*)(Bw + (size_t)n * ldb + k0 + lk);
        else       bv = make_float4(0.f, 0.f, 0.f, 0.f);
        __syncthreads();
        As[lk + 0][lr] = av.x; As[lk + 1][lr] = av.y; As[lk + 2][lr] = av.z; As[lk + 3][lr] = av.w;
        Bs[lk + 0][lr] = bv.x; Bs[lk + 1][lr] = bv.y; Bs[lk + 2][lr] = bv.z; Bs[lk + 3][lr] = bv.w;
        __syncthreads();
#pragma unroll
        for (int kk = 0; kk < BK; kk++) {
            float4 a4 = *(const float4*)&As[kk][ty * 4];
            float4 b4 = *(const float4*)&Bs[kk][tx * 4];
            float ar[4] = {a4.x, a4.y, a4.z, a4.w};
            float br[4] = {b4.x, b4.y, b4.z, b4.w};
#pragma unroll
            for (int i = 0; i < 4; i++)
#pragma unroll
                for (int j = 0; j < 4; j++)
                    acc[i][j] = fmaf(ar[i], br[j], acc[i][j]);
        }
    }
#pragma unroll
    for (int i = 0; i < 4; i++) {
        int m = m0 + ty * 4 + i;
#pragma unroll
        for (int j = 0; j < 4; j++) {
            int n = n0 + tx * 4 + j;
            if (n < N) C[(size_t)m * ldc + n] = acc[i][j];
        }
    }
}

// ---------------- dt = softplus(raw + dt_bias); dA = exp(-exp(Alog)*dt) ----------------
__global__ __launch_bounds__(256) void k_dtda(const float* __restrict__ zx, const float* __restrict__ dtb,
                                              const float* __restrict__ Alog,
                                              float* __restrict__ dt, float* __restrict__ dA) {
    int i = blockIdx.x * 256 + threadIdx.x;
    if (i >= B_ * L_ * NH) return;
    int hh = i % NH;
    int bl = i / NH;
    float v = zx[(size_t)bl * DIP + DI + CD + hh] + dtb[hh];
    float dtv = (v > 20.f) ? v : log1pf(expf(v));
    float dAv = expf(-expf(Alog[hh]) * dtv);
    dt[i] = dtv;
    dA[i] = dAv;
}

// ---------------- causal depthwise conv (k=4) + bias + silu ----------------
__global__ __launch_bounds__(256) void k_conv(const float* __restrict__ zx, const float* __restrict__ cw,
                                              const float* __restrict__ cb, float* __restrict__ out) {
    int i = blockIdx.x * 256 + threadIdx.x;
    if (i >= B_ * L_ * CD) return;
    int c = i % CD;
    int bl = i / CD;
    int l = bl % L_;
    int b = bl / L_;
    float acc = cb[c];
#pragma unroll
    for (int k = 0; k < 4; k++) {
        int ls = l - 3 + k;
        if (ls >= 0) acc = fmaf(zx[((size_t)b * L_ + ls) * DIP + DI + c], cw[c * 4 + k], acc);
    }
    out[i] = acc / (1.f + expf(-acc));   // silu
}

// ---------------- sequential scan, in-place y into conv[...,0..512) ----------------
__global__ __launch_bounds__(256) void k_scan(float* __restrict__ conv, const float* __restrict__ dt,
                                              const float* __restrict__ dA, const float* __restrict__ Dp) {
    int b = blockIdx.x >> 3, h = blockIdx.x & 7;
    int tid = threadIdx.x;
    int p = tid >> 2, ng = tid & 3, n0 = ng * 4;
    __shared__ float xs_s[2][CHUNK][HD];
    __shared__ float bc_s[2][CHUNK][32];
    __shared__ float dd_s[2][CHUNK][2];
    float st[4] = {0.f, 0.f, 0.f, 0.f};
    float Dval = Dp[h];
    float* base = conv + (size_t)b * L_ * CD;

    // load chunk c into buffer buf
    auto load = [&](int c, int buf) {
        int t0 = c * CHUNK;
        for (int idx = tid; idx < CHUNK * 96; idx += 256) {
            int s_ = idx / 96, j = idx - s_ * 96;
            const float* row = base + (size_t)(t0 + s_) * CD;
            if (j < HD) xs_s[buf][s_][j] = row[h * HD + j];
            else        bc_s[buf][s_][j - HD] = row[DI + (j - HD)];
        }
        if (tid < 2 * CHUNK) {
            int s_ = tid >> 1, w = tid & 1;
            int gi = (b * L_ + t0 + s_) * NH + h;
            dd_s[buf][s_][w] = w ? dt[gi] : dA[gi];
        }
    };

    load(0, 0);
    __syncthreads();
    const int nc = L_ / CHUNK;
    for (int c = 0; c < nc; c++) {
        int buf = c & 1;
        if (c + 1 < nc) load(c + 1, buf ^ 1);
        int t0 = c * CHUNK;
#pragma unroll
        for (int s_ = 0; s_ < CHUNK; s_++) {
            float dAv = dd_s[buf][s_][0];
            float dtv = dd_s[buf][s_][1];
            float xv = xs_s[buf][s_][p];
            float dtx = dtv * xv;
            float y = 0.f;
#pragma unroll
            for (int j = 0; j < 4; j++) {
                float Bv = bc_s[buf][s_][n0 + j];
                float Cv = bc_s[buf][s_][16 + n0 + j];
                st[j] = fmaf(dAv, st[j], dtx * Bv);
                y = fmaf(st[j], Cv, y);
            }
            y += __shfl_xor(y, 1);
            y += __shfl_xor(y, 2);
            if (ng == 0) base[(size_t)(t0 + s_) * CD + h * HD + p] = fmaf(Dval, xv, y);
        }
        __syncthreads();
    }
}

// ---------------- gated RMSNorm: yn = (y*silu(z)) * rsqrt(mean(sq)+eps) * nw, into zx[...,0..512) ----------------
__global__ __launch_bounds__(256) void k_gatedrms(const float* __restrict__ conv, float* __restrict__ zx,
                                                  const float* __restrict__ nw) {
    int bl = blockIdx.x;
    int tid = threadIdx.x;
    const float* yrow = conv + (size_t)bl * CD;
    float* zrow = zx + (size_t)bl * DIP;
    float v[2];
    float ss = 0.f;
#pragma unroll
    for (int q = 0; q < 2; q++) {
        int c = tid + q * 256;
        float z = zrow[c];
        float y = yrow[c] * (z / (1.f + expf(-z)));
        v[q] = y;
        ss = fmaf(y, y, ss);
    }
#pragma unroll
    for (int m = 1; m < 64; m <<= 1) ss += __shfl_xor(ss, m);
    __shared__ float red[4];
    if ((tid & 63) == 0) red[tid >> 6] = ss;
    __syncthreads();
    float r = rsqrtf((red[0] + red[1] + red[2] + red[3]) * (1.f / DI) + 1e-5f);
#pragma unroll
    for (int q = 0; q < 2; q++) {
        int c = tid + q * 256;
        zrow[c] = v[q] * r * nw[c];
    }
}

// ---------------- residual add + LayerNorm + mask, into h ----------------
__global__ __launch_bounds__(256) void k_ln(const float* __restrict__ tmp, float* __restrict__ h,
                                            const float* __restrict__ lnw, const float* __restrict__ lnb,
                                            const float* __restrict__ mask) {
    int bl = blockIdx.x;
    int tid = threadIdx.x;
    size_t idx = (size_t)bl * DM + tid;
    float v = tmp[idx] + h[idx];
    __shared__ float red[4];
    float s = v;
#pragma unroll
    for (int m = 1; m < 64; m <<= 1) s += __shfl_xor(s, m);
    if ((tid & 63) == 0) red[tid >> 6] = s;
    __syncthreads();
    float mu = (red[0] + red[1] + red[2] + red[3]) * (1.f / DM);
    float d = v - mu;
    float q = d * d;
    __syncthreads();
#pragma unroll
    for (int m = 1; m < 64; m <<= 1) q += __shfl_xor(q, m);
    if ((tid & 63) == 0) red[tid >> 6] = q;
    __syncthreads();
    float var = (red[0] + red[1] + red[2] + red[3]) * (1.f / DM);
    h[idx] = (d * rsqrtf(var + 1e-5f) * lnw[tid] + lnb[tid]) * mask[bl];
}

// ---------------- mean-pool over L + classifier ----------------
__global__ __launch_bounds__(256) void k_pool_cls(const float* __restrict__ h, const float* __restrict__ cw,
                                                  const float* __restrict__ cb, float* __restrict__ out) {
    int b = blockIdx.x, tid = threadIdx.x;
    float s = 0.f;
    const float* hb = h + (size_t)b * L_ * DM + tid;
    for (int l = 0; l < L_; l++) s += hb[(size_t)l * DM];
    s *= (1.0f / L_);
    float p0 = s * cw[tid];
    float p1 = s * cw[DM + tid];
#pragma unroll
    for (int m = 1; m < 64; m <<= 1) {
        p0 += __shfl_xor(p0, m);
        p1 += __shfl_xor(p1, m);
    }
    __shared__ float r0[4], r1[4];
    if ((tid & 63) == 0) { r0[tid >> 6] = p0; r1[tid >> 6] = p1; }
    __syncthreads();
    if (tid == 0) {
        out[b * 2 + 0] = r0[0] + r0[1] + r0[2] + r0[3] + cb[0];
        out[b * 2 + 1] = r1[0] + r1[1] + r1[2] + r1[3] + cb[1];
    }
}

extern "C" void kernel_launch(void* const* d_in, const int* in_sizes, int n_in,
                              void* d_out, int out_size, void* d_ws, size_t ws_size,
                              hipStream_t stream) {
    const int*   x    = (const int*)d_in[0];
    const float* mask = (const float*)d_in[1];
    const float* emb  = (const float*)d_in[2];
    const float* pos  = (const float*)d_in[3];
    const float* Wi   = (const float*)d_in[4];
    const float* cw   = (const float*)d_in[5];
    const float* cb   = (const float*)d_in[6];
    const float* dtb  = (const float*)d_in[7];
    const float* Alog = (const float*)d_in[8];
    const float* Dp   = (const float*)d_in[9];
    const float* nw   = (const float*)d_in[10];
    const float* Wo   = (const float*)d_in[11];
    const float* lnw  = (const float*)d_in[12];
    const float* lnb  = (const float*)d_in[13];
    const float* clsw = (const float*)d_in[14];
    const float* clsb = (const float*)d_in[15];
    float* out = (float*)d_out;

    float* ws   = (float*)d_ws;
    float* h    = ws;
    float* zx   = h + (size_t)B_ * L_ * DM;     // 16384 x 1064
    float* conv = zx + (size_t)B_ * L_ * DIP;   // 16384 x 544 (also reused as out_proj tmp 16384 x 256)
    float* dt   = conv + (size_t)B_ * L_ * CD;  // 16384 x 8
    float* dA   = dt + (size_t)B_ * L_ * NH;    // 16384 x 8

    k_embed<<<(B_ * L_ * DM + 255) / 256, 256, 0, stream>>>(x, mask, emb, pos, h);

    for (int i = 0; i < 4; i++) {
        // zxbcdt = h @ Wi^T   (16384 x 1064)
        k_gemm_nt<<<dim3(B_ * L_ / 64, (DIP + 63) / 64), 256, 0, stream>>>(
            h, DM, Wi + (size_t)i * DIP * DM, DM, zx, DIP, B_ * L_, DIP, DM);
        // dt / dA
        k_dtda<<<(B_ * L_ * NH + 255) / 256, 256, 0, stream>>>(zx, dtb + i * NH, Alog + i * NH, dt, dA);
        // conv + silu
        k_conv<<<(B_ * L_ * CD + 255) / 256, 256, 0, stream>>>(zx, cw + (size_t)i * CD * 4, cb + i * CD, conv);
        // sequential scan (writes y into conv[...,0..512) in place)
        k_scan<<<64, 256, 0, stream>>>(conv, dt, dA, Dp + i * NH);
        // gated RMSNorm (writes into zx[...,0..512))
        k_gatedrms<<<B_ * L_, 256, 0, stream>>>(conv, zx, nw + (size_t)i * DI);
        // out = yn @ Wo^T  (16384 x 256) into conv-region tmp
        k_gemm_nt<<<dim3(B_ * L_ / 64, DM / 64), 256, 0, stream>>>(
            zx, DIP, Wo + (size_t)i * DM * DI, DI, conv, DM, B_ * L_, DM, DI);
        // h = LN(tmp + h) * mask
        k_ln<<<B_ * L_, 256, 0, stream>>>(conv, h, lnw, lnb, mask);
    }

    k_pool_cls<<<B_, 256, 0, stream>>>(h, clsw, clsb, out);
}

// Round 2
// 1504.141 us; speedup vs baseline: 2.6765x; 2.6765x over previous
//
#include <hip/hip_runtime.h>
#include <hip/hip_bf16.h>
#include <math.h>

#define B_ 8
#define L_ 2048
#define DM 256
#define DIP 1064
#define DI 512
#define CD 544
#define DSZ 16
#define NH 8
#define HD 64
#define Q_ 64
#define NC 32

// ---------------- embed: h = emb[x] + pos, * mask ----------------
__global__ __launch_bounds__(256) void k_embed(const int* __restrict__ x, const float* __restrict__ mask,
                                               const float* __restrict__ emb, const float* __restrict__ pos,
                                               float* __restrict__ h) {
    int i = blockIdx.x * 256 + threadIdx.x;
    if (i >= B_ * L_ * DM) return;
    int d = i % DM;
    int bl = i / DM;
    int l = bl % L_;
    int tok = x[bl];
    h[i] = (emb[tok * DM + d] + pos[l * DM + d]) * mask[bl];
}

// ---------------- fp32 NT GEMM: C[m,n] = sum_k A[m,k]*Bw[n,k] ----------------
__global__ __launch_bounds__(256) void k_gemm_nt(const float* __restrict__ A, int lda,
                                                 const float* __restrict__ Bw, int ldb,
                                                 float* __restrict__ C, int ldc,
                                                 int M, int N, int K) {
    const int BM = 64, BN = 64, BK = 16;
    __shared__ float As[BK][BM];
    __shared__ float Bs[BK][BN];
    int tid = threadIdx.x;
    int tx = tid & 15, ty = tid >> 4;
    int m0 = blockIdx.x * BM, n0 = blockIdx.y * BN;
    int lr = tid >> 2;
    int lk = (tid & 3) * 4;
    float acc[4][4] = {};
    for (int k0 = 0; k0 < K; k0 += BK) {
        float4 av = *(const float4*)(A + (size_t)(m0 + lr) * lda + k0 + lk);
        float4 bv;
        int n = n0 + lr;
        if (n < N) bv = *(const float4*)(Bw + (size_t)n * ldb + k0 + lk);
        else       bv = make_float4(0.f, 0.f, 0.f, 0.f);
        __syncthreads();
        As[lk + 0][lr] = av.x; As[lk + 1][lr] = av.y; As[lk + 2][lr] = av.z; As[lk + 3][lr] = av.w;
        Bs[lk + 0][lr] = bv.x; Bs[lk + 1][lr] = bv.y; Bs[lk + 2][lr] = bv.z; Bs[lk + 3][lr] = bv.w;
        __syncthreads();
#pragma unroll
        for (int kk = 0; kk < BK; kk++) {
            float4 a4 = *(const float4*)&As[kk][ty * 4];
            float4 b4 = *(const float4*)&Bs[kk][tx * 4];
            float ar[4] = {a4.x, a4.y, a4.z, a4.w};
            float br[4] = {b4.x, b4.y, b4.z, b4.w};
#pragma unroll
            for (int i = 0; i < 4; i++)
#pragma unroll
                for (int j = 0; j < 4; j++)
                    acc[i][j] = fmaf(ar[i], br[j], acc[i][j]);
        }
    }
#pragma unroll
    for (int i = 0; i < 4; i++) {
        int m = m0 + ty * 4 + i;
#pragma unroll
        for (int j = 0; j < 4; j++) {
            int n = n0 + tx * 4 + j;
            if (n < N) C[(size_t)m * ldc + n] = acc[i][j];
        }
    }
}

// ---------------- dt = softplus(raw + dt_bias); ldA = -exp(Alog)*dt ----------------
__global__ __launch_bounds__(256) void k_dtda(const float* __restrict__ zx, const float* __restrict__ dtb,
                                              const float* __restrict__ Alog,
                                              float* __restrict__ dt, float* __restrict__ ldA) {
    int i = blockIdx.x * 256 + threadIdx.x;
    if (i >= B_ * L_ * NH) return;
    int hh = i % NH;
    int bl = i / NH;
    float v = zx[(size_t)bl * DIP + DI + CD + hh] + dtb[hh];
    float dtv = (v > 20.f) ? v : log1pf(expf(v));
    dt[i] = dtv;
    ldA[i] = -expf(Alog[hh]) * dtv;
}

// ---------------- causal depthwise conv (k=4) + bias + silu ----------------
__global__ __launch_bounds__(256) void k_conv(const float* __restrict__ zx, const float* __restrict__ cw,
                                              const float* __restrict__ cb, float* __restrict__ out) {
    int i = blockIdx.x * 256 + threadIdx.x;
    if (i >= B_ * L_ * CD) return;
    int c = i % CD;
    int bl = i / CD;
    int l = bl % L_;
    int b = bl / L_;
    float acc = cb[c];
#pragma unroll
    for (int k = 0; k < 4; k++) {
        int ls = l - 3 + k;
        if (ls >= 0) acc = fmaf(zx[((size_t)b * L_ + ls) * DIP + DI + c], cw[c * 4 + k], acc);
    }
    out[i] = acc / (1.f + expf(-acc));   // silu
}

// ---------------- chunked scan, stage 1: intra-chunk y (in place) + chunk state ----------------
__global__ __launch_bounds__(256) void k_scan1(float* __restrict__ conv, const float* __restrict__ dt,
                                               const float* __restrict__ ldA, const float* __restrict__ Dp,
                                               float* __restrict__ Sg, float* __restrict__ Pg,
                                               float* __restrict__ cumLg) {
    int bh = blockIdx.x, c = blockIdx.y;
    int b = bh >> 3, h = bh & 7;
    int tid = threadIdx.x;
    int t0 = c * Q_;
    __shared__ float Xs[Q_][HD];      // 16 KB
    __shared__ float Bs[Q_][DSZ];     // 4 KB
    __shared__ float Cs[Q_][DSZ];     // 4 KB
    __shared__ float CB[Q_][Q_ + 1];  // 16.25 KB : dt_s * dot(C_t,B_s)
    __shared__ float Lc[Q_], dts[Q_], coefS[Q_];
    float* base = conv + ((size_t)b * L_ + t0) * CD;

    {   // load X tile
        int r = tid >> 2, c0 = (tid & 3) * 16;
        const float* src = base + (size_t)r * CD + h * HD + c0;
#pragma unroll
        for (int k = 0; k < 4; k++)
            *(float4*)&Xs[r][c0 + 4 * k] = *(const float4*)(src + 4 * k);
    }
    if (tid < 128) {   // load B, C tiles
        int r = tid >> 1, half = tid & 1;
        const float* src = base + (size_t)r * CD + DI + half * 16;
        float* dst = half ? &Cs[r][0] : &Bs[r][0];
#pragma unroll
        for (int k = 0; k < 4; k++) *(float4*)(dst + 4 * k) = *(const float4*)(src + 4 * k);
    }
    if (tid < 64) {    // dt, ldA + inclusive log-cumsum (wave 0)
        int gi = ((b * L_) + t0 + tid) * NH + h;
        dts[tid] = dt[gi];
        float v = ldA[gi];
#pragma unroll
        for (int off = 1; off < 64; off <<= 1) {
            float u = __shfl_up(v, off);
            if (tid >= off) v += u;
        }
        Lc[tid] = v;
    }
    __syncthreads();
    float Lend = Lc[Q_ - 1];
    if (tid < 64) coefS[tid] = __expf(Lend - Lc[tid]) * dts[tid];

    // phase 1: CB[t][s] = dt_s * dot16(C_t, B_s)
    {
        int t = tid >> 2, s0 = (tid & 3) * 16;
        float Cr[16];
#pragma unroll
        for (int k = 0; k < 16; k++) Cr[k] = Cs[t][k];
        for (int j = 0; j < 16; j++) {
            int s = s0 + j;
            float d = 0.f;
#pragma unroll
            for (int k = 0; k < 16; k++) d = fmaf(Cr[k], Bs[s][k], d);
            CB[t][s] = d * dts[s];
        }
    }
    __syncthreads();

    // phase 2: Y[t][p] = D*x + sum_{s<=t} exp(Lc_t-Lc_s)*CB[t][s]*x_s[p]
    {
        int t = tid >> 2, p0 = (tid & 3) * 16;
        float Dval = Dp[h];
        float Y[16];
#pragma unroll
        for (int j = 0; j < 16; j++) Y[j] = Dval * Xs[t][p0 + j];
        float Lt = Lc[t];
        for (int s = 0; s <= t; s++) {
            float g = __expf(Lt - Lc[s]) * CB[t][s];
#pragma unroll
            for (int j = 0; j < 16; j++) Y[j] = fmaf(g, Xs[s][p0 + j], Y[j]);
        }
        float* dst = base + (size_t)t * CD + h * HD + p0;
#pragma unroll
        for (int k = 0; k < 4; k++)
            *(float4*)(dst + 4 * k) = make_float4(Y[4 * k], Y[4 * k + 1], Y[4 * k + 2], Y[4 * k + 3]);
    }

    // phase 3: chunk state S[p][n] = sum_s coefS[s]*x_s[p]*B_s[n]
    {
        int p = tid >> 2, n0 = (tid & 3) * 4;
        float S0 = 0, S1 = 0, S2 = 0, S3 = 0;
        for (int s = 0; s < Q_; s++) {
            float a = coefS[s] * Xs[s][p];
            S0 = fmaf(a, Bs[s][n0 + 0], S0);
            S1 = fmaf(a, Bs[s][n0 + 1], S1);
            S2 = fmaf(a, Bs[s][n0 + 2], S2);
            S3 = fmaf(a, Bs[s][n0 + 3], S3);
        }
        size_t sb = ((size_t)(bh * NC + c) * HD + p) * DSZ + n0;
        *(float4*)(Sg + sb) = make_float4(S0, S1, S2, S3);
    }
    if (tid < 64) cumLg[(size_t)(bh * NC + c) * Q_ + tid] = Lc[tid];
    if (tid == 0) Pg[bh * NC + c] = __expf(Lend);
}

// ---------------- chunked scan, stage 2: sequential combine of chunk states ----------------
__global__ __launch_bounds__(256) void k_scan2(const float* __restrict__ Sg, const float* __restrict__ Pg,
                                               float* __restrict__ Hg) {
    int bh = blockIdx.x;
    int tid = threadIdx.x;
    int p = tid >> 2, n0 = (tid & 3) * 4;
    float4 H = make_float4(0.f, 0.f, 0.f, 0.f);
    for (int c = 0; c < NC; c++) {
        size_t base = ((size_t)(bh * NC + c) * HD + p) * DSZ + n0;
        float P = Pg[bh * NC + c];
        float4 S = *(const float4*)(Sg + base);
        *(float4*)(Hg + base) = H;   // state BEFORE chunk c
        H.x = fmaf(P, H.x, S.x);
        H.y = fmaf(P, H.y, S.y);
        H.z = fmaf(P, H.z, S.z);
        H.w = fmaf(P, H.w, S.w);
    }
}

// ---------------- chunked scan, stage 3: add cross-chunk term in place ----------------
__global__ __launch_bounds__(256) void k_scan3(float* __restrict__ conv, const float* __restrict__ Hg,
                                               const float* __restrict__ cumLg) {
    int bh = blockIdx.x, c = blockIdx.y;
    int b = bh >> 3, h = bh & 7;
    int tid = threadIdx.x;
    int t0 = c * Q_;
    __shared__ float Hs[HD][DSZ + 1];
    {
        int p = tid >> 2, n0 = (tid & 3) * 4;
        float4 v = *(const float4*)(Hg + ((size_t)(bh * NC + c) * HD + p) * DSZ + n0);
        Hs[p][n0] = v.x; Hs[p][n0 + 1] = v.y; Hs[p][n0 + 2] = v.z; Hs[p][n0 + 3] = v.w;
    }
    __syncthreads();
    int t = tid >> 2, p0 = (tid & 3) * 16;
    float* row = conv + ((size_t)b * L_ + t0 + t) * CD;
    float Cr[16];
#pragma unroll
    for (int k = 0; k < 4; k++) {
        float4 v = *(const float4*)(row + DI + DSZ + 4 * k);
        Cr[4 * k] = v.x; Cr[4 * k + 1] = v.y; Cr[4 * k + 2] = v.z; Cr[4 * k + 3] = v.w;
    }
    float f = __expf(cumLg[(size_t)(bh * NC + c) * Q_ + t]);
#pragma unroll
    for (int k = 0; k < 4; k++) {
        float4 yv = *(const float4*)(row + h * HD + p0 + 4 * k);
        float m[4];
#pragma unroll
        for (int j = 0; j < 4; j++) {
            int p = p0 + 4 * k + j;
            float d = 0.f;
#pragma unroll
            for (int n = 0; n < 16; n++) d = fmaf(Cr[n], Hs[p][n], d);
            m[j] = d;
        }
        yv.x = fmaf(f, m[0], yv.x);
        yv.y = fmaf(f, m[1], yv.y);
        yv.z = fmaf(f, m[2], yv.z);
        yv.w = fmaf(f, m[3], yv.w);
        *(float4*)(row + h * HD + p0 + 4 * k) = yv;
    }
}

// ---------------- gated RMSNorm ----------------
__global__ __launch_bounds__(256) void k_gatedrms(const float* __restrict__ conv, float* __restrict__ zx,
                                                  const float* __restrict__ nw) {
    int bl = blockIdx.x;
    int tid = threadIdx.x;
    const float* yrow = conv + (size_t)bl * CD;
    float* zrow = zx + (size_t)bl * DIP;
    float v[2];
    float ss = 0.f;
#pragma unroll
    for (int q = 0; q < 2; q++) {
        int c = tid + q * 256;
        float z = zrow[c];
        float y = yrow[c] * (z / (1.f + expf(-z)));
        v[q] = y;
        ss = fmaf(y, y, ss);
    }
#pragma unroll
    for (int m = 1; m < 64; m <<= 1) ss += __shfl_xor(ss, m);
    __shared__ float red[4];
    if ((tid & 63) == 0) red[tid >> 6] = ss;
    __syncthreads();
    float r = rsqrtf((red[0] + red[1] + red[2] + red[3]) * (1.f / DI) + 1e-5f);
#pragma unroll
    for (int q = 0; q < 2; q++) {
        int c = tid + q * 256;
        zrow[c] = v[q] * r * nw[c];
    }
}

// ---------------- residual add + LayerNorm + mask ----------------
__global__ __launch_bounds__(256) void k_ln(const float* __restrict__ tmp, float* __restrict__ h,
                                            const float* __restrict__ lnw, const float* __restrict__ lnb,
                                            const float* __restrict__ mask) {
    int bl = blockIdx.x;
    int tid = threadIdx.x;
    size_t idx = (size_t)bl * DM + tid;
    float v = tmp[idx] + h[idx];
    __shared__ float red[4];
    float s = v;
#pragma unroll
    for (int m = 1; m < 64; m <<= 1) s += __shfl_xor(s, m);
    if ((tid & 63) == 0) red[tid >> 6] = s;
    __syncthreads();
    float mu = (red[0] + red[1] + red[2] + red[3]) * (1.f / DM);
    float d = v - mu;
    float q = d * d;
    __syncthreads();
#pragma unroll
    for (int m = 1; m < 64; m <<= 1) q += __shfl_xor(q, m);
    if ((tid & 63) == 0) red[tid >> 6] = q;
    __syncthreads();
    float var = (red[0] + red[1] + red[2] + red[3]) * (1.f / DM);
    h[idx] = (d * rsqrtf(var + 1e-5f) * lnw[tid] + lnb[tid]) * mask[bl];
}

// ---------------- mean-pool over L + classifier ----------------
__global__ __launch_bounds__(256) void k_pool_cls(const float* __restrict__ h, const float* __restrict__ cw,
                                                  const float* __restrict__ cb, float* __restrict__ out) {
    int b = blockIdx.x, tid = threadIdx.x;
    float s = 0.f;
    const float* hb = h + (size_t)b * L_ * DM + tid;
    for (int l = 0; l < L_; l++) s += hb[(size_t)l * DM];
    s *= (1.0f / L_);
    float p0 = s * cw[tid];
    float p1 = s * cw[DM + tid];
#pragma unroll
    for (int m = 1; m < 64; m <<= 1) {
        p0 += __shfl_xor(p0, m);
        p1 += __shfl_xor(p1, m);
    }
    __shared__ float r0[4], r1[4];
    if ((tid & 63) == 0) { r0[tid >> 6] = p0; r1[tid >> 6] = p1; }
    __syncthreads();
    if (tid == 0) {
        out[b * 2 + 0] = r0[0] + r0[1] + r0[2] + r0[3] + cb[0];
        out[b * 2 + 1] = r1[0] + r1[1] + r1[2] + r1[3] + cb[1];
    }
}

extern "C" void kernel_launch(void* const* d_in, const int* in_sizes, int n_in,
                              void* d_out, int out_size, void* d_ws, size_t ws_size,
                              hipStream_t stream) {
    const int*   x    = (const int*)d_in[0];
    const float* mask = (const float*)d_in[1];
    const float* emb  = (const float*)d_in[2];
    const float* pos  = (const float*)d_in[3];
    const float* Wi   = (const float*)d_in[4];
    const float* cw   = (const float*)d_in[5];
    const float* cb   = (const float*)d_in[6];
    const float* dtb  = (const float*)d_in[7];
    const float* Alog = (const float*)d_in[8];
    const float* Dp   = (const float*)d_in[9];
    const float* nw   = (const float*)d_in[10];
    const float* Wo   = (const float*)d_in[11];
    const float* lnw  = (const float*)d_in[12];
    const float* lnb  = (const float*)d_in[13];
    const float* clsw = (const float*)d_in[14];
    const float* clsb = (const float*)d_in[15];
    float* out = (float*)d_out;

    float* ws   = (float*)d_ws;
    float* h    = ws;
    float* zx   = h + (size_t)B_ * L_ * DM;       // 16384 x 1064
    float* conv = zx + (size_t)B_ * L_ * DIP;     // 16384 x 544 (also out_proj tmp)
    float* dt   = conv + (size_t)B_ * L_ * CD;    // 16384 x 8
    float* ldA  = dt + (size_t)B_ * L_ * NH;      // 16384 x 8
    float* Sg   = ldA + (size_t)B_ * L_ * NH;     // 64*32*64*16
    float* Pg   = Sg + (size_t)64 * NC * HD * DSZ; // 64*32
    float* cumL = Pg + (size_t)64 * NC;           // 64*32*64
    float* Hg   = cumL + (size_t)64 * NC * Q_;    // 64*32*64*16

    k_embed<<<(B_ * L_ * DM + 255) / 256, 256, 0, stream>>>(x, mask, emb, pos, h);

    for (int i = 0; i < 4; i++) {
        k_gemm_nt<<<dim3(B_ * L_ / 64, (DIP + 63) / 64), 256, 0, stream>>>(
            h, DM, Wi + (size_t)i * DIP * DM, DM, zx, DIP, B_ * L_, DIP, DM);
        k_dtda<<<(B_ * L_ * NH + 255) / 256, 256, 0, stream>>>(zx, dtb + i * NH, Alog + i * NH, dt, ldA);
        k_conv<<<(B_ * L_ * CD + 255) / 256, 256, 0, stream>>>(zx, cw + (size_t)i * CD * 4, cb + i * CD, conv);
        k_scan1<<<dim3(64, NC), 256, 0, stream>>>(conv, dt, ldA, Dp + i * NH, Sg, Pg, cumL);
        k_scan2<<<64, 256, 0, stream>>>(Sg, Pg, Hg);
        k_scan3<<<dim3(64, NC), 256, 0, stream>>>(conv, Hg, cumL);
        k_gatedrms<<<B_ * L_, 256, 0, stream>>>(conv, zx, nw + (size_t)i * DI);
        k_gemm_nt<<<dim3(B_ * L_ / 64, DM / 64), 256, 0, stream>>>(
            zx, DIP, Wo + (size_t)i * DM * DI, DI, conv, DM, B_ * L_, DM, DI);
        k_ln<<<B_ * L_, 256, 0, stream>>>(conv, h, lnw, lnb, mask);
    }

    k_pool_cls<<<B_, 256, 0, stream>>>(h, clsw, clsb, out);
}

// Round 3
// 831.723 us; speedup vs baseline: 4.8404x; 1.8085x over previous
//
#include <hip/hip_runtime.h>
#include <hip/hip_bf16.h>
#include <math.h>

#define B_ 8
#define L_ 2048
#define DM 256
#define DIP 1064
#define DI 512
#define CD 544
#define DSZ 16
#define NH 8
#define HD 64
#define Q_ 64
#define NC 32

typedef __attribute__((ext_vector_type(8))) short bf16x8;
typedef __attribute__((ext_vector_type(4))) float f32x4;

__device__ inline unsigned short f2bf(float f) {
    __hip_bfloat16 h = __float2bfloat16(f);
    return *(unsigned short*)&h;
}

// ---------------- fp32 -> bf16 bulk convert (4 elems/thread) ----------------
__global__ __launch_bounds__(256) void k_f2bf(const float* __restrict__ in, unsigned short* __restrict__ out, int n4) {
    int i = blockIdx.x * 256 + threadIdx.x;
    if (i >= n4) return;
    float4 v = *(const float4*)(in + (size_t)i * 4);
    ushort4 o;
    o.x = f2bf(v.x); o.y = f2bf(v.y); o.z = f2bf(v.z); o.w = f2bf(v.w);
    *(ushort4*)(out + (size_t)i * 4) = o;
}

// ---------------- embed: h = emb[x] + pos, * mask  (+ bf16 copy) ----------------
__global__ __launch_bounds__(256) void k_embed(const int* __restrict__ x, const float* __restrict__ mask,
                                               const float* __restrict__ emb, const float* __restrict__ pos,
                                               float* __restrict__ h, unsigned short* __restrict__ h_bf) {
    int i = blockIdx.x * 256 + threadIdx.x;
    if (i >= B_ * L_ * DM) return;
    int d = i % DM;
    int bl = i / DM;
    int l = bl % L_;
    int tok = x[bl];
    float v = (emb[tok * DM + d] + pos[l * DM + d]) * mask[bl];
    h[i] = v;
    h_bf[i] = f2bf(v);
}

// ---------------- bf16 MFMA NT GEMM: C[m,n] = sum_k A[m,k]*Bw[n,k] ----------------
// BM=BN=128, BK=32, 256 threads = 4 waves (2x2 of 64x64), double-buffered LDS,
// staged via global_load_lds width=16. M must be /128; N guarded (clamp+mask).
__global__ __launch_bounds__(256) void k_gemm_bf16(const unsigned short* __restrict__ A, int lda,
                                                   const unsigned short* __restrict__ Bw, int ldb, int N,
                                                   float* __restrict__ C, int ldc, int K) {
    __shared__ unsigned short Al[2][128 * 32];
    __shared__ unsigned short Bl[2][128 * 32];
    int tid = threadIdx.x;
    int l = tid & 63;
    int w = tid >> 6, wr = w >> 1, wc = w & 1;
    int m0 = blockIdx.x * 128, n0 = blockIdx.y * 128;

    f32x4 zero = {0.f, 0.f, 0.f, 0.f};
    f32x4 acc[4][4];
#pragma unroll
    for (int i = 0; i < 4; i++)
#pragma unroll
        for (int j = 0; j < 4; j++) acc[i][j] = zero;

    int lr = l & 15, kq = l >> 4;
    int aoff = (wr * 64 + lr) * 32 + kq * 8;
    int boff = (wc * 64 + lr) * 32 + kq * 8;

    auto stage = [&](int ks, int buf) {
        int k0 = ks * 32;
#pragma unroll
        for (int q = 0; q < 2; q++) {
            int c = tid + q * 256;
            int row = c >> 2, cc = (c & 3) * 8;
            const unsigned short* ga = A + (size_t)(m0 + row) * lda + k0 + cc;
            __builtin_amdgcn_global_load_lds((const __attribute__((address_space(1))) void*)ga,
                                             (__attribute__((address_space(3))) void*)(&Al[buf][c * 8]), 16, 0, 0);
            int rowb = n0 + row;
            if (rowb > N - 1) rowb = N - 1;
            const unsigned short* gb = Bw + (size_t)rowb * ldb + k0 + cc;
            __builtin_amdgcn_global_load_lds((const __attribute__((address_space(1))) void*)gb,
                                             (__attribute__((address_space(3))) void*)(&Bl[buf][c * 8]), 16, 0, 0);
        }
    };

    stage(0, 0);
    int ksteps = K / 32;
    for (int s = 0; s < ksteps; s++) {
        int buf = s & 1;
        __syncthreads();                       // drains staging of buf; protects buf^1 overwrite
        if (s + 1 < ksteps) stage(s + 1, buf ^ 1);
        bf16x8 a[4], b[4];
#pragma unroll
        for (int i = 0; i < 4; i++) a[i] = *(const bf16x8*)&Al[buf][aoff + i * 512];
#pragma unroll
        for (int j = 0; j < 4; j++) b[j] = *(const bf16x8*)&Bl[buf][boff + j * 512];
#pragma unroll
        for (int i = 0; i < 4; i++)
#pragma unroll
            for (int j = 0; j < 4; j++)
                acc[i][j] = __builtin_amdgcn_mfma_f32_16x16x32_bf16(a[i], b[j], acc[i][j], 0, 0, 0);
    }

#pragma unroll
    for (int i = 0; i < 4; i++) {
        int m = m0 + wr * 64 + i * 16 + (l >> 4) * 4;
#pragma unroll
        for (int j = 0; j < 4; j++) {
            int n = n0 + wc * 64 + j * 16 + (l & 15);
            if (n < N) {
#pragma unroll
                for (int r = 0; r < 4; r++)
                    C[(size_t)(m + r) * ldc + n] = acc[i][j][r];
            }
        }
    }
}

// ---------------- dt = softplus(raw + dt_bias); ldA = -exp(Alog)*dt ----------------
__global__ __launch_bounds__(256) void k_dtda(const float* __restrict__ zx, const float* __restrict__ dtb,
                                              const float* __restrict__ Alog,
                                              float* __restrict__ dt, float* __restrict__ ldA) {
    int i = blockIdx.x * 256 + threadIdx.x;
    if (i >= B_ * L_ * NH) return;
    int hh = i % NH;
    int bl = i / NH;
    float v = zx[(size_t)bl * DIP + DI + CD + hh] + dtb[hh];
    float dtv = (v > 20.f) ? v : log1pf(expf(v));
    dt[i] = dtv;
    ldA[i] = -expf(Alog[hh]) * dtv;
}

// ---------------- causal depthwise conv (k=4) + bias + silu ----------------
__global__ __launch_bounds__(256) void k_conv(const float* __restrict__ zx, const float* __restrict__ cw,
                                              const float* __restrict__ cb, float* __restrict__ out) {
    int i = blockIdx.x * 256 + threadIdx.x;
    if (i >= B_ * L_ * CD) return;
    int c = i % CD;
    int bl = i / CD;
    int l = bl % L_;
    int b = bl / L_;
    float acc = cb[c];
#pragma unroll
    for (int k = 0; k < 4; k++) {
        int ls = l - 3 + k;
        if (ls >= 0) acc = fmaf(zx[((size_t)b * L_ + ls) * DIP + DI + c], cw[c * 4 + k], acc);
    }
    out[i] = acc / (1.f + expf(-acc));   // silu
}

// ---------------- chunked scan, stage 1 ----------------
__global__ __launch_bounds__(256) void k_scan1(float* __restrict__ conv, const float* __restrict__ dt,
                                               const float* __restrict__ ldA, const float* __restrict__ Dp,
                                               float* __restrict__ Sg, float* __restrict__ Pg,
                                               float* __restrict__ cumLg) {
    int bh = blockIdx.x, c = blockIdx.y;
    int b = bh >> 3, h = bh & 7;
    int tid = threadIdx.x;
    int t0 = c * Q_;
    __shared__ float Xs[Q_][HD];
    __shared__ float Bs[Q_][DSZ];
    __shared__ float Cs[Q_][DSZ];
    __shared__ float CB[Q_][Q_ + 1];
    __shared__ float Lc[Q_], dts[Q_], coefS[Q_];
    float* base = conv + ((size_t)b * L_ + t0) * CD;

    {
        int r = tid >> 2, c0 = (tid & 3) * 16;
        const float* src = base + (size_t)r * CD + h * HD + c0;
#pragma unroll
        for (int k = 0; k < 4; k++)
            *(float4*)&Xs[r][c0 + 4 * k] = *(const float4*)(src + 4 * k);
    }
    if (tid < 128) {
        int r = tid >> 1, half = tid & 1;
        const float* src = base + (size_t)r * CD + DI + half * 16;
        float* dst = half ? &Cs[r][0] : &Bs[r][0];
#pragma unroll
        for (int k = 0; k < 4; k++) *(float4*)(dst + 4 * k) = *(const float4*)(src + 4 * k);
    }
    if (tid < 64) {
        int gi = ((b * L_) + t0 + tid) * NH + h;
        dts[tid] = dt[gi];
        float v = ldA[gi];
#pragma unroll
        for (int off = 1; off < 64; off <<= 1) {
            float u = __shfl_up(v, off);
            if (tid >= off) v += u;
        }
        Lc[tid] = v;
    }
    __syncthreads();
    float Lend = Lc[Q_ - 1];
    if (tid < 64) coefS[tid] = __expf(Lend - Lc[tid]) * dts[tid];

    {
        int t = tid >> 2, s0 = (tid & 3) * 16;
        float Cr[16];
#pragma unroll
        for (int k = 0; k < 16; k++) Cr[k] = Cs[t][k];
        for (int j = 0; j < 16; j++) {
            int s = s0 + j;
            float d = 0.f;
#pragma unroll
            for (int k = 0; k < 16; k++) d = fmaf(Cr[k], Bs[s][k], d);
            CB[t][s] = d * dts[s];
        }
    }
    __syncthreads();

    {
        int t = tid >> 2, p0 = (tid & 3) * 16;
        float Dval = Dp[h];
        float Y[16];
#pragma unroll
        for (int j = 0; j < 16; j++) Y[j] = Dval * Xs[t][p0 + j];
        float Lt = Lc[t];
        for (int s = 0; s <= t; s++) {
            float g = __expf(Lt - Lc[s]) * CB[t][s];
#pragma unroll
            for (int j = 0; j < 16; j++) Y[j] = fmaf(g, Xs[s][p0 + j], Y[j]);
        }
        float* dst = base + (size_t)t * CD + h * HD + p0;
#pragma unroll
        for (int k = 0; k < 4; k++)
            *(float4*)(dst + 4 * k) = make_float4(Y[4 * k], Y[4 * k + 1], Y[4 * k + 2], Y[4 * k + 3]);
    }

    {
        int p = tid >> 2, n0 = (tid & 3) * 4;
        float S0 = 0, S1 = 0, S2 = 0, S3 = 0;
        for (int s = 0; s < Q_; s++) {
            float a = coefS[s] * Xs[s][p];
            S0 = fmaf(a, Bs[s][n0 + 0], S0);
            S1 = fmaf(a, Bs[s][n0 + 1], S1);
            S2 = fmaf(a, Bs[s][n0 + 2], S2);
            S3 = fmaf(a, Bs[s][n0 + 3], S3);
        }
        size_t sb = ((size_t)(bh * NC + c) * HD + p) * DSZ + n0;
        *(float4*)(Sg + sb) = make_float4(S0, S1, S2, S3);
    }
    if (tid < 64) cumLg[(size_t)(bh * NC + c) * Q_ + tid] = Lc[tid];
    if (tid == 0) Pg[bh * NC + c] = __expf(Lend);
}

// ---------------- chunked scan, stage 2 ----------------
__global__ __launch_bounds__(256) void k_scan2(const float* __restrict__ Sg, const float* __restrict__ Pg,
                                               float* __restrict__ Hg) {
    int bh = blockIdx.x;
    int tid = threadIdx.x;
    int p = tid >> 2, n0 = (tid & 3) * 4;
    float4 H = make_float4(0.f, 0.f, 0.f, 0.f);
    for (int c = 0; c < NC; c++) {
        size_t base = ((size_t)(bh * NC + c) * HD + p) * DSZ + n0;
        float P = Pg[bh * NC + c];
        float4 S = *(const float4*)(Sg + base);
        *(float4*)(Hg + base) = H;
        H.x = fmaf(P, H.x, S.x);
        H.y = fmaf(P, H.y, S.y);
        H.z = fmaf(P, H.z, S.z);
        H.w = fmaf(P, H.w, S.w);
    }
}

// ---------------- chunked scan, stage 3 ----------------
__global__ __launch_bounds__(256) void k_scan3(float* __restrict__ conv, const float* __restrict__ Hg,
                                               const float* __restrict__ cumLg) {
    int bh = blockIdx.x, c = blockIdx.y;
    int b = bh >> 3, h = bh & 7;
    int tid = threadIdx.x;
    int t0 = c * Q_;
    __shared__ float Hs[HD][DSZ + 1];
    {
        int p = tid >> 2, n0 = (tid & 3) * 4;
        float4 v = *(const float4*)(Hg + ((size_t)(bh * NC + c) * HD + p) * DSZ + n0);
        Hs[p][n0] = v.x; Hs[p][n0 + 1] = v.y; Hs[p][n0 + 2] = v.z; Hs[p][n0 + 3] = v.w;
    }
    __syncthreads();
    int t = tid >> 2, p0 = (tid & 3) * 16;
    float* row = conv + ((size_t)b * L_ + t0 + t) * CD;
    float Cr[16];
#pragma unroll
    for (int k = 0; k < 4; k++) {
        float4 v = *(const float4*)(row + DI + DSZ + 4 * k);
        Cr[4 * k] = v.x; Cr[4 * k + 1] = v.y; Cr[4 * k + 2] = v.z; Cr[4 * k + 3] = v.w;
    }
    float f = __expf(cumLg[(size_t)(bh * NC + c) * Q_ + t]);
#pragma unroll
    for (int k = 0; k < 4; k++) {
        float4 yv = *(const float4*)(row + h * HD + p0 + 4 * k);
        float m[4];
#pragma unroll
        for (int j = 0; j < 4; j++) {
            int p = p0 + 4 * k + j;
            float d = 0.f;
#pragma unroll
            for (int n = 0; n < 16; n++) d = fmaf(Cr[n], Hs[p][n], d);
            m[j] = d;
        }
        yv.x = fmaf(f, m[0], yv.x);
        yv.y = fmaf(f, m[1], yv.y);
        yv.z = fmaf(f, m[2], yv.z);
        yv.w = fmaf(f, m[3], yv.w);
        *(float4*)(row + h * HD + p0 + 4 * k) = yv;
    }
}

// ---------------- gated RMSNorm -> bf16 yn ----------------
__global__ __launch_bounds__(256) void k_gatedrms(const float* __restrict__ conv, const float* __restrict__ zx,
                                                  unsigned short* __restrict__ yn_bf, const float* __restrict__ nw) {
    int bl = blockIdx.x;
    int tid = threadIdx.x;
    const float* yrow = conv + (size_t)bl * CD;
    const float* zrow = zx + (size_t)bl * DIP;
    float v[2];
    float ss = 0.f;
#pragma unroll
    for (int q = 0; q < 2; q++) {
        int c = tid + q * 256;
        float z = zrow[c];
        float y = yrow[c] * (z / (1.f + expf(-z)));
        v[q] = y;
        ss = fmaf(y, y, ss);
    }
#pragma unroll
    for (int m = 1; m < 64; m <<= 1) ss += __shfl_xor(ss, m);
    __shared__ float red[4];
    if ((tid & 63) == 0) red[tid >> 6] = ss;
    __syncthreads();
    float r = rsqrtf((red[0] + red[1] + red[2] + red[3]) * (1.f / DI) + 1e-5f);
#pragma unroll
    for (int q = 0; q < 2; q++) {
        int c = tid + q * 256;
        yn_bf[(size_t)bl * DI + c] = f2bf(v[q] * r * nw[c]);
    }
}

// ---------------- residual add + LayerNorm + mask (+ bf16 copy) ----------------
__global__ __launch_bounds__(256) void k_ln(const float* __restrict__ tmp, float* __restrict__ h,
                                            unsigned short* __restrict__ h_bf,
                                            const float* __restrict__ lnw, const float* __restrict__ lnb,
                                            const float* __restrict__ mask) {
    int bl = blockIdx.x;
    int tid = threadIdx.x;
    size_t idx = (size_t)bl * DM + tid;
    float v = tmp[idx] + h[idx];
    __shared__ float red[4];
    float s = v;
#pragma unroll
    for (int m = 1; m < 64; m <<= 1) s += __shfl_xor(s, m);
    if ((tid & 63) == 0) red[tid >> 6] = s;
    __syncthreads();
    float mu = (red[0] + red[1] + red[2] + red[3]) * (1.f / DM);
    float d = v - mu;
    float q = d * d;
    __syncthreads();
#pragma unroll
    for (int m = 1; m < 64; m <<= 1) q += __shfl_xor(q, m);
    if ((tid & 63) == 0) red[tid >> 6] = q;
    __syncthreads();
    float var = (red[0] + red[1] + red[2] + red[3]) * (1.f / DM);
    float o = (d * rsqrtf(var + 1e-5f) * lnw[tid] + lnb[tid]) * mask[bl];
    h[idx] = o;
    h_bf[idx] = f2bf(o);
}

// ---------------- mean-pool over L + classifier ----------------
__global__ __launch_bounds__(256) void k_pool_cls(const float* __restrict__ h, const float* __restrict__ cw,
                                                  const float* __restrict__ cb, float* __restrict__ out) {
    int b = blockIdx.x, tid = threadIdx.x;
    float s = 0.f;
    const float* hb = h + (size_t)b * L_ * DM + tid;
    for (int l = 0; l < L_; l++) s += hb[(size_t)l * DM];
    s *= (1.0f / L_);
    float p0 = s * cw[tid];
    float p1 = s * cw[DM + tid];
#pragma unroll
    for (int m = 1; m < 64; m <<= 1) {
        p0 += __shfl_xor(p0, m);
        p1 += __shfl_xor(p1, m);
    }
    __shared__ float r0[4], r1[4];
    if ((tid & 63) == 0) { r0[tid >> 6] = p0; r1[tid >> 6] = p1; }
    __syncthreads();
    if (tid == 0) {
        out[b * 2 + 0] = r0[0] + r0[1] + r0[2] + r0[3] + cb[0];
        out[b * 2 + 1] = r1[0] + r1[1] + r1[2] + r1[3] + cb[1];
    }
}

extern "C" void kernel_launch(void* const* d_in, const int* in_sizes, int n_in,
                              void* d_out, int out_size, void* d_ws, size_t ws_size,
                              hipStream_t stream) {
    const int*   x    = (const int*)d_in[0];
    const float* mask = (const float*)d_in[1];
    const float* emb  = (const float*)d_in[2];
    const float* pos  = (const float*)d_in[3];
    const float* Wi   = (const float*)d_in[4];
    const float* cw   = (const float*)d_in[5];
    const float* cb   = (const float*)d_in[6];
    const float* dtb  = (const float*)d_in[7];
    const float* Alog = (const float*)d_in[8];
    const float* Dp   = (const float*)d_in[9];
    const float* nw   = (const float*)d_in[10];
    const float* Wo   = (const float*)d_in[11];
    const float* lnw  = (const float*)d_in[12];
    const float* lnb  = (const float*)d_in[13];
    const float* clsw = (const float*)d_in[14];
    const float* clsb = (const float*)d_in[15];
    float* out = (float*)d_out;

    float* ws   = (float*)d_ws;
    float* h    = ws;
    float* zx   = h + (size_t)B_ * L_ * DM;
    float* conv = zx + (size_t)B_ * L_ * DIP;
    float* dt   = conv + (size_t)B_ * L_ * CD;
    float* ldA  = dt + (size_t)B_ * L_ * NH;
    float* Sg   = ldA + (size_t)B_ * L_ * NH;
    float* Pg   = Sg + (size_t)64 * NC * HD * DSZ;
    float* cumL = Pg + (size_t)64 * NC;
    float* Hg   = cumL + (size_t)64 * NC * Q_;
    unsigned short* h_bf  = (unsigned short*)(Hg + (size_t)64 * NC * HD * DSZ);
    unsigned short* yn_bf = h_bf + (size_t)B_ * L_ * DM;
    unsigned short* Wi_bf = yn_bf + (size_t)B_ * L_ * DI;
    unsigned short* Wo_bf = Wi_bf + (size_t)4 * DIP * DM;

    // convert weights to bf16 (every launch; deterministic)
    k_f2bf<<<(4 * DIP * DM / 4 + 255) / 256, 256, 0, stream>>>(Wi, Wi_bf, 4 * DIP * DM / 4);
    k_f2bf<<<(4 * DM * DI / 4 + 255) / 256, 256, 0, stream>>>(Wo, Wo_bf, 4 * DM * DI / 4);

    k_embed<<<(B_ * L_ * DM + 255) / 256, 256, 0, stream>>>(x, mask, emb, pos, h, h_bf);

    for (int i = 0; i < 4; i++) {
        // zxbcdt = h @ Wi^T   (16384 x 1064), bf16 MFMA
        k_gemm_bf16<<<dim3(B_ * L_ / 128, (DIP + 127) / 128), 256, 0, stream>>>(
            h_bf, DM, Wi_bf + (size_t)i * DIP * DM, DM, DIP, zx, DIP, DM);
        k_dtda<<<(B_ * L_ * NH + 255) / 256, 256, 0, stream>>>(zx, dtb + i * NH, Alog + i * NH, dt, ldA);
        k_conv<<<(B_ * L_ * CD + 255) / 256, 256, 0, stream>>>(zx, cw + (size_t)i * CD * 4, cb + i * CD, conv);
        k_scan1<<<dim3(64, NC), 256, 0, stream>>>(conv, dt, ldA, Dp + i * NH, Sg, Pg, cumL);
        k_scan2<<<64, 256, 0, stream>>>(Sg, Pg, Hg);
        k_scan3<<<dim3(64, NC), 256, 0, stream>>>(conv, Hg, cumL);
        k_gatedrms<<<B_ * L_, 256, 0, stream>>>(conv, zx, yn_bf, nw + (size_t)i * DI);
        // out = yn @ Wo^T  (16384 x 256), bf16 MFMA, into conv-region tmp
        k_gemm_bf16<<<dim3(B_ * L_ / 128, DM / 128), 256, 0, stream>>>(
            yn_bf, DI, Wo_bf + (size_t)i * DM * DI, DI, DM, conv, DM, DI);
        k_ln<<<B_ * L_, 256, 0, stream>>>(conv, h, h_bf, lnw, lnb, mask);
    }

    k_pool_cls<<<B_, 256, 0, stream>>>(h, clsw, clsb, out);
}

// Round 4
// 702.918 us; speedup vs baseline: 5.7274x; 1.1832x over previous
//
#include <hip/hip_runtime.h>
#include <hip/hip_bf16.h>
#include <math.h>

#define B_ 8
#define L_ 2048
#define DM 256
#define DIP 1064
#define DI 512
#define CD 544
#define DSZ 16
#define NH 8
#define HD 64
#define Q_ 64
#define NC 32

typedef __attribute__((ext_vector_type(8))) short bf16x8;
typedef __attribute__((ext_vector_type(4))) float f32x4;

__device__ inline unsigned short f2bf(float f) {
    __hip_bfloat16 h = __float2bfloat16(f);
    return *(unsigned short*)&h;
}

// ---------------- fp32 -> bf16 bulk convert ----------------
__global__ __launch_bounds__(256) void k_f2bf(const float* __restrict__ in, unsigned short* __restrict__ out, int n4) {
    int i = blockIdx.x * 256 + threadIdx.x;
    if (i >= n4) return;
    float4 v = *(const float4*)(in + (size_t)i * 4);
    ushort4 o;
    o.x = f2bf(v.x); o.y = f2bf(v.y); o.z = f2bf(v.z); o.w = f2bf(v.w);
    *(ushort4*)(out + (size_t)i * 4) = o;
}

// ---------------- embed ----------------
__global__ __launch_bounds__(256) void k_embed(const int* __restrict__ x, const float* __restrict__ mask,
                                               const float* __restrict__ emb, const float* __restrict__ pos,
                                               float* __restrict__ h, unsigned short* __restrict__ h_bf) {
    int i = blockIdx.x * 256 + threadIdx.x;
    if (i >= B_ * L_ * DM) return;
    int d = i % DM;
    int bl = i / DM;
    int l = bl % L_;
    int tok = x[bl];
    float v = (emb[tok * DM + d] + pos[l * DM + d]) * mask[bl];
    h[i] = v;
    h_bf[i] = f2bf(v);
}

// ---------------- bf16 MFMA NT GEMM (128x128 tile, BK=32, global_load_lds) ----------------
__global__ __launch_bounds__(256) void k_gemm_bf16(const unsigned short* __restrict__ A, int lda,
                                                   const unsigned short* __restrict__ Bw, int ldb, int N,
                                                   float* __restrict__ C, int ldc, int K) {
    __shared__ unsigned short Al[2][128 * 32];
    __shared__ unsigned short Bl[2][128 * 32];
    int tid = threadIdx.x;
    int l = tid & 63;
    int w = tid >> 6, wr = w >> 1, wc = w & 1;
    int m0 = blockIdx.x * 128, n0 = blockIdx.y * 128;

    f32x4 zero = {0.f, 0.f, 0.f, 0.f};
    f32x4 acc[4][4];
#pragma unroll
    for (int i = 0; i < 4; i++)
#pragma unroll
        for (int j = 0; j < 4; j++) acc[i][j] = zero;

    int lr = l & 15, kq = l >> 4;
    int aoff = (wr * 64 + lr) * 32 + kq * 8;
    int boff = (wc * 64 + lr) * 32 + kq * 8;

    auto stage = [&](int ks, int buf) {
        int k0 = ks * 32;
#pragma unroll
        for (int q = 0; q < 2; q++) {
            int c = tid + q * 256;
            int row = c >> 2, cc = (c & 3) * 8;
            const unsigned short* ga = A + (size_t)(m0 + row) * lda + k0 + cc;
            __builtin_amdgcn_global_load_lds((const __attribute__((address_space(1))) void*)ga,
                                             (__attribute__((address_space(3))) void*)(&Al[buf][c * 8]), 16, 0, 0);
            int rowb = n0 + row;
            if (rowb > N - 1) rowb = N - 1;
            const unsigned short* gb = Bw + (size_t)rowb * ldb + k0 + cc;
            __builtin_amdgcn_global_load_lds((const __attribute__((address_space(1))) void*)gb,
                                             (__attribute__((address_space(3))) void*)(&Bl[buf][c * 8]), 16, 0, 0);
        }
    };

    stage(0, 0);
    int ksteps = K / 32;
    for (int s = 0; s < ksteps; s++) {
        int buf = s & 1;
        __syncthreads();
        if (s + 1 < ksteps) stage(s + 1, buf ^ 1);
        bf16x8 a[4], b[4];
#pragma unroll
        for (int i = 0; i < 4; i++) a[i] = *(const bf16x8*)&Al[buf][aoff + i * 512];
#pragma unroll
        for (int j = 0; j < 4; j++) b[j] = *(const bf16x8*)&Bl[buf][boff + j * 512];
#pragma unroll
        for (int i = 0; i < 4; i++)
#pragma unroll
            for (int j = 0; j < 4; j++)
                acc[i][j] = __builtin_amdgcn_mfma_f32_16x16x32_bf16(a[i], b[j], acc[i][j], 0, 0, 0);
    }

#pragma unroll
    for (int i = 0; i < 4; i++) {
        int m = m0 + wr * 64 + i * 16 + (l >> 4) * 4;
#pragma unroll
        for (int j = 0; j < 4; j++) {
            int n = n0 + wc * 64 + j * 16 + (l & 15);
            if (n < N) {
#pragma unroll
                for (int r = 0; r < 4; r++)
                    C[(size_t)(m + r) * ldc + n] = acc[i][j][r];
            }
        }
    }
}

// ---------------- conv (k=4, bias, silu) + fused dt/ldA ----------------
__global__ __launch_bounds__(256) void k_convdt(const float* __restrict__ zx, const float* __restrict__ cw,
                                                const float* __restrict__ cb, float* __restrict__ out,
                                                const float* __restrict__ dtb, const float* __restrict__ Alog,
                                                float* __restrict__ dt, float* __restrict__ ldA) {
    int i = blockIdx.x * 256 + threadIdx.x;
    if (i >= B_ * L_ * CD) return;
    int c = i % CD;
    int bl = i / CD;
    int l = bl % L_;
    int b = bl / L_;
    float acc = cb[c];
#pragma unroll
    for (int k = 0; k < 4; k++) {
        int ls = l - 3 + k;
        if (ls >= 0) acc = fmaf(zx[((size_t)b * L_ + ls) * DIP + DI + c], cw[c * 4 + k], acc);
    }
    out[i] = acc / (1.f + __expf(-acc));   // silu
    if (c < NH) {
        float v = zx[(size_t)bl * DIP + DI + CD + c] + dtb[c];
        float dtv = (v > 20.f) ? v : log1pf(__expf(v));
        dt[bl * NH + c] = dtv;
        ldA[bl * NH + c] = -__expf(Alog[c]) * dtv;
    }
}

// ---------------- chunked scan stage 1 (MFMA): intra-chunk Y + chunk state ----------------
__global__ __launch_bounds__(256) void k_scan1m(float* __restrict__ conv, const float* __restrict__ dt,
                                                const float* __restrict__ ldA, const float* __restrict__ Dp,
                                                float* __restrict__ Sg, float* __restrict__ Pg,
                                                float* __restrict__ cumLg) {
    int bh = blockIdx.x, c = blockIdx.y;
    int b = bh >> 3, h = bh & 7;
    int tid = threadIdx.x;
    int t0 = c * Q_;
    int w = tid >> 6, l = tid & 63;
    int lr = l & 15, kq = l >> 4;

    __shared__ __align__(16) float Xs[Q_][HD];          // 16 KB fp32 X
    __shared__ __align__(16) float Bsf[Q_][DSZ];        // 4 KB
    __shared__ __align__(16) float Csf[Q_][DSZ];        // 4 KB
    __shared__ __align__(16) unsigned short Xt[Q_ * 72];   // bf16 X^T [p][s], stride 72
    __shared__ __align__(16) unsigned short Cbf[Q_ * 32];  // bf16 C padded K32, swz
    __shared__ __align__(16) unsigned short Bbf[Q_ * 32];  // bf16 dt*B padded K32, swz
    __shared__ __align__(16) unsigned short Btw[DSZ * 72]; // bf16 coef*B^T [n][s]
    __shared__ __align__(16) unsigned short Mbf[Q_ * 64];  // bf16 decay matrix, swz
    __shared__ float Lc[Q_], dts[Q_], coefS[Q_];

    float* base = conv + ((size_t)b * L_ + t0) * CD;
    float Dval = Dp[h];

    {   // load X tile (fp32, coalesced)
        int r = tid >> 2, c0 = (tid & 3) * 16;
        const float* src = base + (size_t)r * CD + h * HD + c0;
#pragma unroll
        for (int k = 0; k < 4; k++)
            *(float4*)&Xs[r][c0 + 4 * k] = *(const float4*)(src + 4 * k);
    }
    if (tid < 128) {   // load B, C (fp32)
        int r = tid >> 1, half = tid & 1;
        const float* src = base + (size_t)r * CD + DI + half * 16;
        float* dst = half ? &Csf[r][0] : &Bsf[r][0];
#pragma unroll
        for (int k = 0; k < 4; k++) *(float4*)(dst + 4 * k) = *(const float4*)(src + 4 * k);
    }
    if (tid < 64) {    // cumsum of ldA (wave 0), coefs, global chunk meta
        int gi = ((b * L_) + t0 + tid) * NH + h;
        dts[tid] = dt[gi];
        float v = ldA[gi];
#pragma unroll
        for (int off = 1; off < 64; off <<= 1) {
            float u = __shfl_up(v, off);
            if (tid >= off) v += u;
        }
        Lc[tid] = v;
        float lend = __shfl(v, 63);
        coefS[tid] = __expf(lend - v) * dts[tid];
        cumLg[(size_t)(bh * NC + c) * Q_ + tid] = v;
        if (tid == 63) Pg[bh * NC + c] = __expf(v);
    }
    __syncthreads();

    // build bf16 operands
    {   // Cbf / Bbf (K padded to 32, dt folded into B), kblk-swizzled by row&3
        int t = tid & 63, kb = tid >> 6;
        int swz = (kb ^ (t & 3)) * 8;
        bf16x8 cv, bv;
        float dtv = dts[t];
#pragma unroll
        for (int j = 0; j < 8; j++) {
            int k = kb * 8 + j;
            float cf = (k < DSZ) ? Csf[t][k] : 0.f;
            float bf = (k < DSZ) ? dtv * Bsf[t][k] : 0.f;
            cv[j] = (short)f2bf(cf);
            bv[j] = (short)f2bf(bf);
        }
        *(bf16x8*)&Cbf[t * 32 + swz] = cv;
        *(bf16x8*)&Bbf[t * 32 + swz] = bv;
    }
    {   // Xt[p][s] = bf16(X[s][p])
        int p = tid & 63, sb = tid >> 6;
        bf16x8 lo, hi;
#pragma unroll
        for (int j = 0; j < 8; j++) {
            lo[j] = (short)f2bf(Xs[sb * 16 + j][p]);
            hi[j] = (short)f2bf(Xs[sb * 16 + 8 + j][p]);
        }
        *(bf16x8*)&Xt[p * 72 + sb * 16] = lo;
        *(bf16x8*)&Xt[p * 72 + sb * 16 + 8] = hi;
    }
    if (tid < 128) {   // Btw[n][s] = bf16(coefS[s] * B[s][n])
        int n = tid >> 3, sb = tid & 7;
        bf16x8 v;
#pragma unroll
        for (int j = 0; j < 8; j++) {
            int s = sb * 8 + j;
            v[j] = (short)f2bf(coefS[s] * Bsf[s][n]);
        }
        *(bf16x8*)&Btw[n * 72 + sb * 8] = v;
    }
    __syncthreads();

    f32x4 zero = {0.f, 0.f, 0.f, 0.f};

    // phase 1: CB tiles (wave w owns t-tile w), K=32 (zero-padded)
    f32x4 cb[4];
    {
        bf16x8 af = *(const bf16x8*)&Cbf[(w * 16 + lr) * 32 + ((kq ^ (lr & 3)) * 8)];
#pragma unroll
        for (int st = 0; st < 4; st++) {
            bf16x8 bf = *(const bf16x8*)&Bbf[(st * 16 + lr) * 32 + ((kq ^ (lr & 3)) * 8)];
            cb[st] = __builtin_amdgcn_mfma_f32_16x16x32_bf16(af, bf, zero, 0, 0, 0);
        }
    }
    // mask + decay -> Mbf (swizzled by 8-short blocks)
#pragma unroll
    for (int st = 0; st < 4; st++) {
#pragma unroll
        for (int r = 0; r < 4; r++) {
            int t = w * 16 + kq * 4 + r;
            int s = st * 16 + lr;
            float m = (s <= t) ? __expf(Lc[t] - Lc[s]) * cb[st][r] : 0.f;
            Mbf[t * 64 + (((s >> 3) ^ (t & 7)) * 8) + (s & 7)] = f2bf(m);
        }
    }
    __syncthreads();

    // phase 2: Y = M * X^T-op (wave w owns t-tile w), K=64
    {
        f32x4 acc[4];
#pragma unroll
        for (int pt = 0; pt < 4; pt++) acc[pt] = zero;
#pragma unroll
        for (int ks = 0; ks < 2; ks++) {
            bf16x8 af = *(const bf16x8*)&Mbf[(w * 16 + lr) * 64 + (((ks * 4 + kq) ^ (lr & 7)) * 8)];
#pragma unroll
            for (int pt = 0; pt < 4; pt++) {
                bf16x8 bf = *(const bf16x8*)&Xt[(pt * 16 + lr) * 72 + ks * 32 + kq * 8];
                acc[pt] = __builtin_amdgcn_mfma_f32_16x16x32_bf16(af, bf, acc[pt], 0, 0, 0);
            }
        }
#pragma unroll
        for (int pt = 0; pt < 4; pt++) {
#pragma unroll
            for (int r = 0; r < 4; r++) {
                int t = w * 16 + kq * 4 + r;
                int p = pt * 16 + lr;
                base[(size_t)t * CD + h * HD + p] = acc[pt][r] + Dval * Xs[t][p];
            }
        }
    }

    // phase 3: S = X^T * Btw^T-op (wave w owns p-tile w), K=64
    {
        f32x4 sacc = zero;
#pragma unroll
        for (int ks = 0; ks < 2; ks++) {
            bf16x8 af = *(const bf16x8*)&Xt[(w * 16 + lr) * 72 + ks * 32 + kq * 8];
            bf16x8 bf = *(const bf16x8*)&Btw[lr * 72 + ks * 32 + kq * 8];
            sacc = __builtin_amdgcn_mfma_f32_16x16x32_bf16(af, bf, sacc, 0, 0, 0);
        }
#pragma unroll
        for (int r = 0; r < 4; r++) {
            int p = w * 16 + kq * 4 + r;
            Sg[((size_t)(bh * NC + c) * HD + p) * DSZ + lr] = sacc[r];
        }
    }
}

// ---------------- chunked scan stage 2 ----------------
__global__ __launch_bounds__(256) void k_scan2(const float* __restrict__ Sg, const float* __restrict__ Pg,
                                               float* __restrict__ Hg) {
    int bh = blockIdx.x;
    int tid = threadIdx.x;
    int p = tid >> 2, n0 = (tid & 3) * 4;
    float4 H = make_float4(0.f, 0.f, 0.f, 0.f);
    for (int c = 0; c < NC; c++) {
        size_t base = ((size_t)(bh * NC + c) * HD + p) * DSZ + n0;
        float P = Pg[bh * NC + c];
        float4 S = *(const float4*)(Sg + base);
        *(float4*)(Hg + base) = H;
        H.x = fmaf(P, H.x, S.x);
        H.y = fmaf(P, H.y, S.y);
        H.z = fmaf(P, H.z, S.z);
        H.w = fmaf(P, H.w, S.w);
    }
}

// ---------------- chunked scan stage 3 ----------------
__global__ __launch_bounds__(256) void k_scan3(float* __restrict__ conv, const float* __restrict__ Hg,
                                               const float* __restrict__ cumLg) {
    int bh = blockIdx.x, c = blockIdx.y;
    int b = bh >> 3, h = bh & 7;
    int tid = threadIdx.x;
    int t0 = c * Q_;
    __shared__ float Hs[HD][DSZ + 1];
    {
        int p = tid >> 2, n0 = (tid & 3) * 4;
        float4 v = *(const float4*)(Hg + ((size_t)(bh * NC + c) * HD + p) * DSZ + n0);
        Hs[p][n0] = v.x; Hs[p][n0 + 1] = v.y; Hs[p][n0 + 2] = v.z; Hs[p][n0 + 3] = v.w;
    }
    __syncthreads();
    int t = tid >> 2, p0 = (tid & 3) * 16;
    float* row = conv + ((size_t)b * L_ + t0 + t) * CD;
    float Cr[16];
#pragma unroll
    for (int k = 0; k < 4; k++) {
        float4 v = *(const float4*)(row + DI + DSZ + 4 * k);
        Cr[4 * k] = v.x; Cr[4 * k + 1] = v.y; Cr[4 * k + 2] = v.z; Cr[4 * k + 3] = v.w;
    }
    float f = __expf(cumLg[(size_t)(bh * NC + c) * Q_ + t]);
#pragma unroll
    for (int k = 0; k < 4; k++) {
        float4 yv = *(const float4*)(row + h * HD + p0 + 4 * k);
        float m[4];
#pragma unroll
        for (int j = 0; j < 4; j++) {
            int p = p0 + 4 * k + j;
            float d = 0.f;
#pragma unroll
            for (int n = 0; n < 16; n++) d = fmaf(Cr[n], Hs[p][n], d);
            m[j] = d;
        }
        yv.x = fmaf(f, m[0], yv.x);
        yv.y = fmaf(f, m[1], yv.y);
        yv.z = fmaf(f, m[2], yv.z);
        yv.w = fmaf(f, m[3], yv.w);
        *(float4*)(row + h * HD + p0 + 4 * k) = yv;
    }
}

// ---------------- gated RMSNorm -> bf16 yn ----------------
__global__ __launch_bounds__(256) void k_gatedrms(const float* __restrict__ conv, const float* __restrict__ zx,
                                                  unsigned short* __restrict__ yn_bf, const float* __restrict__ nw) {
    int bl = blockIdx.x;
    int tid = threadIdx.x;
    const float* yrow = conv + (size_t)bl * CD;
    const float* zrow = zx + (size_t)bl * DIP;
    float v[2];
    float ss = 0.f;
#pragma unroll
    for (int q = 0; q < 2; q++) {
        int c = tid + q * 256;
        float z = zrow[c];
        float y = yrow[c] * (z / (1.f + __expf(-z)));
        v[q] = y;
        ss = fmaf(y, y, ss);
    }
#pragma unroll
    for (int m = 1; m < 64; m <<= 1) ss += __shfl_xor(ss, m);
    __shared__ float red[4];
    if ((tid & 63) == 0) red[tid >> 6] = ss;
    __syncthreads();
    float r = rsqrtf((red[0] + red[1] + red[2] + red[3]) * (1.f / DI) + 1e-5f);
#pragma unroll
    for (int q = 0; q < 2; q++) {
        int c = tid + q * 256;
        yn_bf[(size_t)bl * DI + c] = f2bf(v[q] * r * nw[c]);
    }
}

// ---------------- residual add + LayerNorm + mask (+ bf16 copy) ----------------
__global__ __launch_bounds__(256) void k_ln(const float* __restrict__ tmp, float* __restrict__ h,
                                            unsigned short* __restrict__ h_bf,
                                            const float* __restrict__ lnw, const float* __restrict__ lnb,
                                            const float* __restrict__ mask) {
    int bl = blockIdx.x;
    int tid = threadIdx.x;
    size_t idx = (size_t)bl * DM + tid;
    float v = tmp[idx] + h[idx];
    __shared__ float red[4];
    float s = v;
#pragma unroll
    for (int m = 1; m < 64; m <<= 1) s += __shfl_xor(s, m);
    if ((tid & 63) == 0) red[tid >> 6] = s;
    __syncthreads();
    float mu = (red[0] + red[1] + red[2] + red[3]) * (1.f / DM);
    float d = v - mu;
    float q = d * d;
    __syncthreads();
#pragma unroll
    for (int m = 1; m < 64; m <<= 1) q += __shfl_xor(q, m);
    if ((tid & 63) == 0) red[tid >> 6] = q;
    __syncthreads();
    float var = (red[0] + red[1] + red[2] + red[3]) * (1.f / DM);
    float o = (d * rsqrtf(var + 1e-5f) * lnw[tid] + lnb[tid]) * mask[bl];
    h[idx] = o;
    h_bf[idx] = f2bf(o);
}

// ---------------- 2-stage mean-pool + classifier ----------------
__global__ __launch_bounds__(256) void k_pool1(const float* __restrict__ h, float* __restrict__ part) {
    int b = blockIdx.x, g = blockIdx.y, d = threadIdx.x;
    const float* hb = h + ((size_t)b * L_ + g * 128) * DM + d;
    float s = 0.f;
    for (int l = 0; l < 128; l++) s += hb[(size_t)l * DM];
    part[((size_t)b * 16 + g) * DM + d] = s;
}

__global__ __launch_bounds__(256) void k_pool2(const float* __restrict__ part, const float* __restrict__ cw,
                                               const float* __restrict__ cb, float* __restrict__ out) {
    int b = blockIdx.x, tid = threadIdx.x;
    float s = 0.f;
#pragma unroll
    for (int g = 0; g < 16; g++) s += part[((size_t)b * 16 + g) * DM + tid];
    s *= (1.0f / L_);
    float p0 = s * cw[tid];
    float p1 = s * cw[DM + tid];
#pragma unroll
    for (int m = 1; m < 64; m <<= 1) {
        p0 += __shfl_xor(p0, m);
        p1 += __shfl_xor(p1, m);
    }
    __shared__ float r0[4], r1[4];
    if ((tid & 63) == 0) { r0[tid >> 6] = p0; r1[tid >> 6] = p1; }
    __syncthreads();
    if (tid == 0) {
        out[b * 2 + 0] = r0[0] + r0[1] + r0[2] + r0[3] + cb[0];
        out[b * 2 + 1] = r1[0] + r1[1] + r1[2] + r1[3] + cb[1];
    }
}

extern "C" void kernel_launch(void* const* d_in, const int* in_sizes, int n_in,
                              void* d_out, int out_size, void* d_ws, size_t ws_size,
                              hipStream_t stream) {
    const int*   x    = (const int*)d_in[0];
    const float* mask = (const float*)d_in[1];
    const float* emb  = (const float*)d_in[2];
    const float* pos  = (const float*)d_in[3];
    const float* Wi   = (const float*)d_in[4];
    const float* cw   = (const float*)d_in[5];
    const float* cb   = (const float*)d_in[6];
    const float* dtb  = (const float*)d_in[7];
    const float* Alog = (const float*)d_in[8];
    const float* Dp   = (const float*)d_in[9];
    const float* nw   = (const float*)d_in[10];
    const float* Wo   = (const float*)d_in[11];
    const float* lnw  = (const float*)d_in[12];
    const float* lnb  = (const float*)d_in[13];
    const float* clsw = (const float*)d_in[14];
    const float* clsb = (const float*)d_in[15];
    float* out = (float*)d_out;

    float* ws   = (float*)d_ws;
    float* h    = ws;
    float* zx   = h + (size_t)B_ * L_ * DM;
    float* conv = zx + (size_t)B_ * L_ * DIP;
    float* dt   = conv + (size_t)B_ * L_ * CD;
    float* ldA  = dt + (size_t)B_ * L_ * NH;
    float* Sg   = ldA + (size_t)B_ * L_ * NH;
    float* Pg   = Sg + (size_t)64 * NC * HD * DSZ;
    float* cumL = Pg + (size_t)64 * NC;
    float* Hg   = cumL + (size_t)64 * NC * Q_;
    float* pool = Hg + (size_t)64 * NC * HD * DSZ;     // 8*16*256
    unsigned short* h_bf  = (unsigned short*)(pool + (size_t)B_ * 16 * DM);
    unsigned short* yn_bf = h_bf + (size_t)B_ * L_ * DM;
    unsigned short* Wi_bf = yn_bf + (size_t)B_ * L_ * DI;
    unsigned short* Wo_bf = Wi_bf + (size_t)4 * DIP * DM;

    k_f2bf<<<(4 * DIP * DM / 4 + 255) / 256, 256, 0, stream>>>(Wi, Wi_bf, 4 * DIP * DM / 4);
    k_f2bf<<<(4 * DM * DI / 4 + 255) / 256, 256, 0, stream>>>(Wo, Wo_bf, 4 * DM * DI / 4);

    k_embed<<<(B_ * L_ * DM + 255) / 256, 256, 0, stream>>>(x, mask, emb, pos, h, h_bf);

    for (int i = 0; i < 4; i++) {
        k_gemm_bf16<<<dim3(B_ * L_ / 128, (DIP + 127) / 128), 256, 0, stream>>>(
            h_bf, DM, Wi_bf + (size_t)i * DIP * DM, DM, DIP, zx, DIP, DM);
        k_convdt<<<(B_ * L_ * CD + 255) / 256, 256, 0, stream>>>(
            zx, cw + (size_t)i * CD * 4, cb + i * CD, conv, dtb + i * NH, Alog + i * NH, dt, ldA);
        k_scan1m<<<dim3(64, NC), 256, 0, stream>>>(conv, dt, ldA, Dp + i * NH, Sg, Pg, cumL);
        k_scan2<<<64, 256, 0, stream>>>(Sg, Pg, Hg);
        k_scan3<<<dim3(64, NC), 256, 0, stream>>>(conv, Hg, cumL);
        k_gatedrms<<<B_ * L_, 256, 0, stream>>>(conv, zx, yn_bf, nw + (size_t)i * DI);
        k_gemm_bf16<<<dim3(B_ * L_ / 128, DM / 128), 256, 0, stream>>>(
            yn_bf, DI, Wo_bf + (size_t)i * DM * DI, DI, DM, conv, DM, DI);
        k_ln<<<B_ * L_, 256, 0, stream>>>(conv, h, h_bf, lnw, lnb, mask);
    }

    k_pool1<<<dim3(B_, 16), 256, 0, stream>>>(h, pool);
    k_pool2<<<B_, 256, 0, stream>>>(pool, clsw, clsb, out);
}